// Round 16
// baseline (67.071 us; speedup 1.0000x reference)
//
#include <hip/hip_runtime.h>
#include <math.h>

typedef _Float16 half8 __attribute__((ext_vector_type(8)));
typedef _Float16 half4v __attribute__((ext_vector_type(4)));
typedef float    f32x4 __attribute__((ext_vector_type(4)));

// ---------------- output offsets (floats) ----------------
#define O_Q     0
#define O_LOSS  2097152
#define O_IDX   2097153
#define O_PERP  2129921
#define O_NECS  2129922
#define O_EMAW  2130946
#define O_W     2196482

// ---------------- workspace offsets (4-byte units) ----------------
#define W_WBF    0          // 65536 fl (=131072 halfs): B-fragments [64ct][4j][64l][8e]
#define W_SW2    65536      // 1024  wsq  (fl32 of fp64 sum)
#define W_RSQ    66560      // 32768 rsq  (fl32 of fp64 sum)
#define W_CNT    132096     // 1024  counts
#define W_DW     133120     // 65536 dw
#define W_LOSS   198656     // 1     loss
#define W_ZN     66561      // floats to zero starting at W_CNT

#define F16_MIN_NORM 6.103515625e-05f   // 2^-14

// =====================================================================
// kernel 0 (prep, grid 256): unchanged from round 10 (verified)
// =====================================================================
__global__ __launch_bounds__(256)
void k_prep(const float* __restrict__ w, const float* __restrict__ x,
            _Float16* __restrict__ wbf, float* __restrict__ wsq,
            float* __restrict__ rsq, float* __restrict__ zbase) {
    __shared__ float sh[64][65];
    int tid = threadIdx.x, blk = blockIdx.x;

    for (int z = blk * 256 + tid; z < W_ZN; z += 256 * 256) zbase[z] = 0.f;

    if (blk < 64) {
        int T  = blk * 256 + tid;           // 0..16383
        int ct = T >> 8, j = (T >> 6) & 3, l = T & 63;
        int kb = j & 1, isLo = j >> 1;
        int c  = ct * 16 + (l & 15), g = l >> 4;
        half8 o;
        #pragma unroll
        for (int e = 0; e < 8; ++e) {
            int kd = kb * 32 + g * 4 + (e & 3) + ((e >> 2) << 4);
            float wv = w[c * 64 + kd];
            _Float16 h = (fabsf(wv) >= F16_MIN_NORM) ? (_Float16)wv : (_Float16)0.f;
            if (isLo) {
                float hf = (float)h;
                o[e] = (_Float16)((wv - hf) * 16384.0f);   // lo scaled 2^14
            } else {
                o[e] = h;
            }
        }
        *(half8*)(wbf + ((ct * 4 + j) * 64 + l) * 8) = o;
    }

    if (blk < 16) {           // wsq
        int j0 = blk * 64;
        for (int p = 0; p < 16; ++p) {
            int f = p * 256 + tid;
            int j = f >> 6, d = f & 63;
            sh[j][d] = w[(j0 + j) * 64 + d];
        }
        __syncthreads();
        if (tid < 64) {
            double s = 0.0;
            #pragma unroll
            for (int d = 0; d < 64; ++d) {
                double v = (double)sh[tid][d];
                s = fma(v, v, s);
            }
            wsq[j0 + tid] = (float)s;
        }
    }

    if (blk >= 128) {         // rsq, one row per thread, d ascending
        int r = (blk - 128) * 256 + tid;
        const float* xp = x + (r >> 10) * 65536 + (r & 1023);
        double s = 0.0;
        #pragma unroll 8
        for (int d = 0; d < 64; ++d) {
            double v = (double)xp[d * 1024];
            s = fma(v, v, s);
        }
        rsq[r] = (float)s;
    }
}

// =====================================================================
// kernel 1 (fused): MFMA distances + argmin + quant/loss/counts/dw.
// Traffic-optimal + TLP structure: grid 1024 x 512 thr (8 waves).
// Block = 32 rows. Each wave = ct-OCTANT (8 cts) x BOTH row-tiles ->
// each B-load feeds 12 MFMAs (256 MB total L2 traffic, the r13 level)
// while 8192 waves demand 32/CU (launch_bounds(512,6) -> <=85 VGPR ->
// 3 blocks/CU = 24 waves). wid-ascending merge = ct-ascending first-min.
// Per-(row,ct) argmin numerics bitwise-identical to rounds 10-15.
// =====================================================================
__global__ __launch_bounds__(512, 6)
void k_dist(const float* __restrict__ x, const _Float16* __restrict__ wbf,
            const float* __restrict__ wsq, const float* __restrict__ rsq_g,
            const float* __restrict__ w,
            float* __restrict__ out_idxf,
            float* __restrict__ outq, float* __restrict__ counts,
            float* __restrict__ dw, float* __restrict__ loss) {
    __shared__ _Float16 xhi[64 * 32];
    __shared__ _Float16 xlo[64 * 32];
    __shared__ float x32[32][65];
    __shared__ float q32[32][65];
    __shared__ float bvs[8][32];
    __shared__ int   bis[8][32];
    __shared__ int   idxl[32];
    __shared__ float red[8];
    int tid = threadIdx.x;
    int rbase = blockIdx.x * 32;
    int b = rbase >> 10, hw0 = rbase & 1023;
    const float* xb = x + b * 65536 + hw0;

    // stage 32 rows -> f16 hi/lo (xlo scaled 2^11) + fp32 copy (1 pass)
    {
        int d = tid >> 3, r4 = (tid & 7) << 2;
        float4 v = *(const float4*)(xb + d * 1024 + r4);
        float vv[4] = {v.x, v.y, v.z, v.w};
        half4v h, lo;
        #pragma unroll
        for (int q = 0; q < 4; ++q) {
            float xv = vv[q];
            _Float16 hh = (fabsf(xv) >= F16_MIN_NORM) ? (_Float16)xv : (_Float16)0.f;
            h[q]  = hh;
            lo[q] = (_Float16)((xv - (float)hh) * 2048.0f);
            x32[r4 + q][d] = xv;
        }
        *(half4v*)&xhi[d * 32 + r4] = h;
        *(half4v*)&xlo[d * 32 + r4] = lo;
    }
    __syncthreads();

    int l   = tid & 63;
    int wid = tid >> 6;          // ct-octant of this wave (0..7)
    int g = l >> 4, n16 = l & 15;

    // A fragments for BOTH row-tiles (resident for the whole ct loop)
    half8 ahi[2][2], alo[2][2];
    #pragma unroll
    for (int t = 0; t < 2; ++t)
        #pragma unroll
        for (int kb = 0; kb < 2; ++kb) {
            #pragma unroll
            for (int e = 0; e < 8; ++e) {
                int kd = kb * 32 + g * 4 + (e & 3) + ((e >> 2) << 4);
                ahi[t][kb][e] = xhi[kd * 32 + t * 16 + n16];
                alo[t][kb][e] = xlo[kd * 32 + t * 16 + n16];
            }
        }

    float rq[2][4];
    #pragma unroll
    for (int t = 0; t < 2; ++t)
        #pragma unroll
        for (int i = 0; i < 4; ++i)
            rq[t][i] = rsq_g[rbase + t * 16 + g * 4 + i];

    float best[2][4];
    int   bidx[2][4];
    #pragma unroll
    for (int t = 0; t < 2; ++t)
        #pragma unroll
        for (int i = 0; i < 4; ++i) { best[t][i] = 3.4e38f; bidx[t][i] = 0; }

    const half8* wv8 = (const half8*)wbf;
    #pragma unroll 1
    for (int c8 = 0; c8 < 8; ++c8) {
        int ct = wid * 8 + c8;
        const half8* wb = wv8 + ct * 256 + l;
        half8 bh0 = wb[0], bh1 = wb[64], bl0 = wb[128], bl1 = wb[192];
        float wsqv = wsq[ct * 16 + n16];
        int n = ct * 16 + n16;

        #pragma unroll
        for (int t = 0; t < 2; ++t) {
            f32x4 c1 = {0.f, 0.f, 0.f, 0.f};
            f32x4 c2 = {0.f, 0.f, 0.f, 0.f};
            f32x4 c3 = {0.f, 0.f, 0.f, 0.f};
            c1 = __builtin_amdgcn_mfma_f32_16x16x32_f16(ahi[t][0], bh0, c1, 0, 0, 0);
            c1 = __builtin_amdgcn_mfma_f32_16x16x32_f16(ahi[t][1], bh1, c1, 0, 0, 0);
            c2 = __builtin_amdgcn_mfma_f32_16x16x32_f16(alo[t][0], bh0, c2, 0, 0, 0);
            c2 = __builtin_amdgcn_mfma_f32_16x16x32_f16(alo[t][1], bh1, c2, 0, 0, 0);
            c3 = __builtin_amdgcn_mfma_f32_16x16x32_f16(ahi[t][0], bl0, c3, 0, 0, 0);
            c3 = __builtin_amdgcn_mfma_f32_16x16x32_f16(ahi[t][1], bl1, c3, 0, 0, 0);

            #pragma unroll
            for (int i = 0; i < 4; ++i) {
                float dot = fmaf(c2[i], 4.8828125e-4f, c1[i]);      // +C2*2^-11
                dot = fmaf(c3[i], 6.103515625e-05f, dot);           // +C3*2^-14
                float t1 = rq[t][i] + wsqv;                         // fl32 add @ ~64
                float sc = fmaf(dot, -2.0f, t1);                    // one rounding
                if (sc < best[t][i]) { best[t][i] = sc; bidx[t][i] = n; }
            }
        }
    }

    // reduce across the 16 lanes of each group (tie -> lower index)
    #pragma unroll
    for (int off = 1; off < 16; off <<= 1) {
        #pragma unroll
        for (int t = 0; t < 2; ++t)
            #pragma unroll
            for (int i = 0; i < 4; ++i) {
                float ov = __shfl_xor(best[t][i], off);
                int   oi = __shfl_xor(bidx[t][i], off);
                if (ov < best[t][i] || (ov == best[t][i] && oi < bidx[t][i])) {
                    best[t][i] = ov; bidx[t][i] = oi;
                }
            }
    }
    if (n16 == 0) {
        #pragma unroll
        for (int t = 0; t < 2; ++t)
            #pragma unroll
            for (int i = 0; i < 4; ++i) {
                bvs[wid][t * 16 + g * 4 + i] = best[t][i];
                bis[wid][t * 16 + g * 4 + i] = bidx[t][i];
            }
    }
    __syncthreads();

    // merge ct-octants per row (wid ascending = ct ascending -> first-min)
    if (tid < 32) {
        float bb = bvs[0][tid]; int ii = bis[0][tid];
        #pragma unroll
        for (int q = 1; q < 8; ++q) {
            float ov = bvs[q][tid]; int oi = bis[q][tid];
            if (ov < bb) { bb = ov; ii = oi; }
        }
        idxl[tid] = ii;
        out_idxf[rbase + tid] = (float)ii;
        atomicAdd(&counts[ii], 1.0f);
    }
    __syncthreads();

    // ---- fused quant phase ----
    // gather codebook rows, quarter-wave float4-coalesced -> LDS (4 rows/wave)
    {
        int n  = wid * 4 + (l >> 4);
        int d4 = (l & 15) << 2;
        *(float4*)&q32[n][d4] = *(const float4*)(w + idxl[n] * 64 + d4);
    }
    __syncthreads();

    float ll = 0.f;
    #pragma unroll
    for (int p = 0; p < 4; ++p) {
        int e = p * 512 + tid;
        int nn = e & 31, d = e >> 5;
        float q  = q32[nn][d];
        float xv = x32[nn][d];
        float dd = q - xv;
        ll += dd * dd;
        outq[b * 65536 + d * 1024 + hw0 + nn] = q;   // coalesced
    }
    #pragma unroll
    for (int off = 32; off; off >>= 1) ll += __shfl_down(ll, off);
    if (l == 0) red[wid] = ll;
    __syncthreads();
    if (tid == 0) {
        float s = 0.f;
        #pragma unroll
        for (int i = 0; i < 8; ++i) s += red[i];
        atomicAdd(loss, s);
    }

    // dw: lane = d, one coalesced 256B atomic row per vector (4 rows/wave)
    #pragma unroll
    for (int v = 0; v < 4; ++v) {
        int n = wid * 4 + v;
        atomicAdd(&dw[idxl[n] * 64 + l], x32[n][l]);
    }
}

// =====================================================================
// kernel 2 (merged finalize, round-9-verified)
// =====================================================================
__global__ __launch_bounds__(256)
void k_final(const float* __restrict__ ema_cs, const float* __restrict__ ema_w,
             const float* __restrict__ counts, const float* __restrict__ dw,
             const float* __restrict__ loss, float* __restrict__ out) {
    __shared__ float cs[1024];
    __shared__ float redA[4], redB[4];
    int tid = threadIdx.x;

    float necs[4];
    float s1 = 0.f, s2 = 0.f;
    #pragma unroll
    for (int q = 0; q < 4; ++q) {
        int j = q * 256 + tid;
        float c  = counts[j];
        float ne = 0.99f * ema_cs[j] + 0.01f * c;
        necs[q] = ne;
        float p = c * (1.0f / 32768.0f);
        s1 += ne;
        s2 += -p * logf(p + 1e-10f);
    }
    #pragma unroll
    for (int off = 32; off; off >>= 1) {
        s1 += __shfl_down(s1, off);
        s2 += __shfl_down(s2, off);
    }
    if ((tid & 63) == 0) { redA[tid >> 6] = s1; redB[tid >> 6] = s2; }
    __syncthreads();
    float ntot = redA[0] + redA[1] + redA[2] + redA[3];
    #pragma unroll
    for (int q = 0; q < 4; ++q)
        cs[q * 256 + tid] = (necs[q] + 1e-5f) / (ntot + 1024.0f * 1e-5f) * ntot;

    if (blockIdx.x == 0) {
        #pragma unroll
        for (int q = 0; q < 4; ++q) out[O_NECS + q * 256 + tid] = necs[q];
        if (tid == 0) {
            out[O_PERP] = expf(redB[0] + redB[1] + redB[2] + redB[3]);
            out[O_LOSS] = 0.25f * loss[0] * (1.0f / 2097152.0f);
        }
    }
    __syncthreads();

    int f = blockIdx.x * 256 + tid;
    int j = f >> 6;
    float ne = 0.99f * ema_w[f] + 0.01f * dw[f];
    out[O_EMAW + f] = ne;
    out[O_W + f]    = ne / cs[j];
}

// =====================================================================
extern "C" void kernel_launch(void* const* d_in, const int* in_sizes, int n_in,
                              void* d_out, int out_size, void* d_ws, size_t ws_size,
                              hipStream_t stream) {
    const float* x      = (const float*)d_in[0];
    const float* w      = (const float*)d_in[1];
    const float* ema_cs = (const float*)d_in[2];
    const float* ema_w  = (const float*)d_in[3];
    float* out = (float*)d_out;
    float* ws  = (float*)d_ws;

    _Float16* wbf  = (_Float16*)(ws + W_WBF);
    float* wsq     = ws + W_SW2;
    float* rsqb    = ws + W_RSQ;
    float* counts  = ws + W_CNT;
    float* dwb     = ws + W_DW;
    float* lossb   = ws + W_LOSS;

    k_prep <<<256,  256, 0, stream>>>(w, x, wbf, wsq, rsqb, counts);
    k_dist <<<1024, 512, 0, stream>>>(x, wbf, wsq, rsqb, w,
                                      out + O_IDX, out + O_Q, counts, dwb, lossb);
    k_final<<<256,  256, 0, stream>>>(ema_cs, ema_w, counts, dwb, lossb, out);
}

// Round 17
// 53.306 us; speedup vs baseline: 1.2582x; 1.2582x over previous
//
#include <hip/hip_runtime.h>
#include <math.h>

typedef _Float16 half8 __attribute__((ext_vector_type(8)));
typedef _Float16 half4v __attribute__((ext_vector_type(4)));
typedef float    f32x4 __attribute__((ext_vector_type(4)));

// ---------------- output offsets (floats) ----------------
#define O_Q     0
#define O_LOSS  2097152
#define O_IDX   2097153
#define O_PERP  2129921
#define O_NECS  2129922
#define O_EMAW  2130946
#define O_W     2196482

// ---------------- workspace offsets (4-byte units) ----------------
#define W_WBF    0          // 65536 fl (=131072 halfs): B-fragments [64ct][4j][64l][8e]
#define W_SW2    65536      // 1024  wsq  (fl32 of fp64 sum)
#define W_RSQ    66560      // 32768 rsq  (fl32 of fp64 sum)
#define W_CNT    132096     // 1024  counts
#define W_DW     133120     // 65536 dw
#define W_LOSS   198656     // 1     loss
#define W_ZN     66561      // floats to zero starting at W_CNT

#define F16_MIN_NORM 6.103515625e-05f   // 2^-14

__device__ __forceinline__ void gload_lds16(const _Float16* g, _Float16* l) {
    __builtin_amdgcn_global_load_lds(
        (const __attribute__((address_space(1))) void*)g,
        (__attribute__((address_space(3))) void*)l, 16, 0, 0);
}

// =====================================================================
// kernel 0 (prep, grid 256): unchanged from round 10 (verified)
// =====================================================================
__global__ __launch_bounds__(256)
void k_prep(const float* __restrict__ w, const float* __restrict__ x,
            _Float16* __restrict__ wbf, float* __restrict__ wsq,
            float* __restrict__ rsq, float* __restrict__ zbase) {
    __shared__ float sh[64][65];
    int tid = threadIdx.x, blk = blockIdx.x;

    for (int z = blk * 256 + tid; z < W_ZN; z += 256 * 256) zbase[z] = 0.f;

    if (blk < 64) {
        int T  = blk * 256 + tid;           // 0..16383
        int ct = T >> 8, j = (T >> 6) & 3, l = T & 63;
        int kb = j & 1, isLo = j >> 1;
        int c  = ct * 16 + (l & 15), g = l >> 4;
        half8 o;
        #pragma unroll
        for (int e = 0; e < 8; ++e) {
            int kd = kb * 32 + g * 4 + (e & 3) + ((e >> 2) << 4);
            float wv = w[c * 64 + kd];
            _Float16 h = (fabsf(wv) >= F16_MIN_NORM) ? (_Float16)wv : (_Float16)0.f;
            if (isLo) {
                float hf = (float)h;
                o[e] = (_Float16)((wv - hf) * 16384.0f);   // lo scaled 2^14
            } else {
                o[e] = h;
            }
        }
        *(half8*)(wbf + ((ct * 4 + j) * 64 + l) * 8) = o;
    }

    if (blk < 16) {           // wsq
        int j0 = blk * 64;
        for (int p = 0; p < 16; ++p) {
            int f = p * 256 + tid;
            int j = f >> 6, d = f & 63;
            sh[j][d] = w[(j0 + j) * 64 + d];
        }
        __syncthreads();
        if (tid < 64) {
            double s = 0.0;
            #pragma unroll
            for (int d = 0; d < 64; ++d) {
                double v = (double)sh[tid][d];
                s = fma(v, v, s);
            }
            wsq[j0 + tid] = (float)s;
        }
    }

    if (blk >= 128) {         // rsq, one row per thread, d ascending
        int r = (blk - 128) * 256 + tid;
        const float* xp = x + (r >> 10) * 65536 + (r & 1023);
        double s = 0.0;
        #pragma unroll 8
        for (int d = 0; d < 64; ++d) {
            double v = (double)xp[d * 1024];
            s = fma(v, v, s);
        }
        rsq[r] = (float)s;
    }
}

// =====================================================================
// kernel 1 (fused): MFMA distances + argmin + quant/loss/counts/dw.
// LDS-staged B: grid 512 x 512 thr (8 waves), block = 64 rows.
// B chunks of 8 cts (32 KB) double-buffered via global_load_lds w=16
// (linear layout; wave-uniform LDS base). Wave = rtp(2 row-halves) x
// cq(4 ct-pairs); per chunk: 2 cts x 2 row-tiles (12 MFMA per B-read).
// Stage chunk t+1 BEFORE computing chunk t; vmcnt(0)+barrier per chunk.
// Per-(row,ct) score numerics bitwise-identical to rounds 10-16; block
// merge carries explicit lower-index tie-break (cq sets interleave).
// =====================================================================
__global__ __launch_bounds__(512, 2)
void k_dist(const float* __restrict__ x, const _Float16* __restrict__ wbf,
            const float* __restrict__ wsq, const float* __restrict__ rsq_g,
            const float* __restrict__ w,
            float* __restrict__ out_idxf,
            float* __restrict__ outq, float* __restrict__ counts,
            float* __restrict__ dw, float* __restrict__ loss) {
    __shared__ _Float16 bstage[2][16384];   // 64 KB: 8 cts x [4j][64l][8e]
    __shared__ _Float16 xhi[64 * 64];       // 8 KB  [kd][row]
    __shared__ _Float16 xlo[64 * 64];       // 8 KB
    __shared__ float x32[64][65];           // 16.6 KB
    __shared__ float q32[64][65];           // 16.6 KB
    __shared__ float wsqs[1024];            // 4 KB
    __shared__ float bvs[8][32];
    __shared__ int   bis[8][32];
    __shared__ int   idxl[64];
    __shared__ float red[8];
    int tid = threadIdx.x;
    int rbase = blockIdx.x * 64;
    int b = rbase >> 10, hw0 = rbase & 1023;
    const float* xb = x + b * 65536 + hw0;

    int l   = tid & 63;
    int wid = tid >> 6;
    int cq  = wid & 3;           // ct-pair within chunk
    int rtp = wid >> 2;          // row-half (32 rows)
    int g = l >> 4, n16 = l & 15;
    int wbase = (tid & ~63) * 8;           // halfs: wave slot in stage buf

    // ---- issue first B chunk, then stage x while it flies ----
    #pragma unroll
    for (int p = 0; p < 4; ++p)
        gload_lds16(wbf + p * 4096 + tid * 8, &bstage[0][p * 4096 + wbase]);

    #pragma unroll
    for (int p = 0; p < 2; ++p) {
        int f = p * 512 + tid;
        int d = f >> 4, r4 = (f & 15) << 2;
        float4 v = *(const float4*)(xb + d * 1024 + r4);
        float vv[4] = {v.x, v.y, v.z, v.w};
        half4v h, lo;
        #pragma unroll
        for (int q = 0; q < 4; ++q) {
            float xv = vv[q];
            _Float16 hh = (fabsf(xv) >= F16_MIN_NORM) ? (_Float16)xv : (_Float16)0.f;
            h[q]  = hh;
            lo[q] = (_Float16)((xv - (float)hh) * 2048.0f);
            x32[r4 + q][d] = xv;
        }
        *(half4v*)&xhi[d * 64 + r4] = h;
        *(half4v*)&xlo[d * 64 + r4] = lo;
    }
    if (tid < 256) ((float4*)wsqs)[tid] = ((const float4*)wsq)[tid];

    asm volatile("s_waitcnt vmcnt(0)" ::: "memory");
    __syncthreads();

    // ---- A fragments for this wave's 2 row-tiles (resident) ----
    half8 ahi[2][2], alo[2][2];
    #pragma unroll
    for (int t = 0; t < 2; ++t)
        #pragma unroll
        for (int kb = 0; kb < 2; ++kb) {
            #pragma unroll
            for (int e = 0; e < 8; ++e) {
                int kd = kb * 32 + g * 4 + (e & 3) + ((e >> 2) << 4);
                int row = rtp * 32 + t * 16 + n16;
                ahi[t][kb][e] = xhi[kd * 64 + row];
                alo[t][kb][e] = xlo[kd * 64 + row];
            }
        }

    float rq[2][4];
    #pragma unroll
    for (int t = 0; t < 2; ++t)
        #pragma unroll
        for (int i = 0; i < 4; ++i)
            rq[t][i] = rsq_g[rbase + rtp * 32 + t * 16 + g * 4 + i];

    float best[2][4];
    int   bidx[2][4];
    #pragma unroll
    for (int t = 0; t < 2; ++t)
        #pragma unroll
        for (int i = 0; i < 4; ++i) { best[t][i] = 3.4e38f; bidx[t][i] = 0; }

    // ---- chunk loop: stage next, compute current ----
    int cur = 0;
    #pragma unroll 1
    for (int ch = 0; ch < 8; ++ch) {
        if (ch < 7) {
            const _Float16* gsrc = wbf + (ch + 1) * 16384;
            #pragma unroll
            for (int p = 0; p < 4; ++p)
                gload_lds16(gsrc + p * 4096 + tid * 8,
                            &bstage[cur ^ 1][p * 4096 + wbase]);
        }

        const _Float16* bb = bstage[cur];
        #pragma unroll
        for (int c2 = 0; c2 < 2; ++c2) {
            int ctl = cq * 2 + c2;
            int ct  = ch * 8 + ctl;
            const half8* wb8 = (const half8*)(bb + ctl * 2048);
            half8 bh0 = wb8[l], bh1 = wb8[64 + l], bl0 = wb8[128 + l], bl1 = wb8[192 + l];
            float wsqv = wsqs[ct * 16 + n16];
            int n = ct * 16 + n16;

            #pragma unroll
            for (int t = 0; t < 2; ++t) {
                f32x4 c1 = {0.f, 0.f, 0.f, 0.f};
                f32x4 c2a = {0.f, 0.f, 0.f, 0.f};
                f32x4 c3 = {0.f, 0.f, 0.f, 0.f};
                c1  = __builtin_amdgcn_mfma_f32_16x16x32_f16(ahi[t][0], bh0, c1, 0, 0, 0);
                c1  = __builtin_amdgcn_mfma_f32_16x16x32_f16(ahi[t][1], bh1, c1, 0, 0, 0);
                c2a = __builtin_amdgcn_mfma_f32_16x16x32_f16(alo[t][0], bh0, c2a, 0, 0, 0);
                c2a = __builtin_amdgcn_mfma_f32_16x16x32_f16(alo[t][1], bh1, c2a, 0, 0, 0);
                c3  = __builtin_amdgcn_mfma_f32_16x16x32_f16(ahi[t][0], bl0, c3, 0, 0, 0);
                c3  = __builtin_amdgcn_mfma_f32_16x16x32_f16(ahi[t][1], bl1, c3, 0, 0, 0);

                #pragma unroll
                for (int i = 0; i < 4; ++i) {
                    float dot = fmaf(c2a[i], 4.8828125e-4f, c1[i]);     // +C2*2^-11
                    dot = fmaf(c3[i], 6.103515625e-05f, dot);           // +C3*2^-14
                    float t1 = rq[t][i] + wsqv;                         // fl32 add @ ~64
                    float sc = fmaf(dot, -2.0f, t1);                    // one rounding
                    if (sc < best[t][i]) { best[t][i] = sc; bidx[t][i] = n; }
                }
            }
        }

        asm volatile("s_waitcnt vmcnt(0)" ::: "memory");
        __syncthreads();
        cur ^= 1;
    }

    // reduce across the 16 lanes of each group (tie -> lower index)
    #pragma unroll
    for (int off = 1; off < 16; off <<= 1) {
        #pragma unroll
        for (int t = 0; t < 2; ++t)
            #pragma unroll
            for (int i = 0; i < 4; ++i) {
                float ov = __shfl_xor(best[t][i], off);
                int   oi = __shfl_xor(bidx[t][i], off);
                if (ov < best[t][i] || (ov == best[t][i] && oi < bidx[t][i])) {
                    best[t][i] = ov; bidx[t][i] = oi;
                }
            }
    }
    if (n16 == 0) {
        #pragma unroll
        for (int t = 0; t < 2; ++t)
            #pragma unroll
            for (int i = 0; i < 4; ++i) {
                bvs[wid][t * 16 + g * 4 + i] = best[t][i];
                bis[wid][t * 16 + g * 4 + i] = bidx[t][i];
            }
    }
    __syncthreads();

    // merge the 4 cq-waves per row-half (explicit lower-index tie-break:
    // cq candidate ct-sets interleave, so value ties need idx compare)
    if (tid < 64) {
        int rh = tid >> 5, lo = tid & 31;
        float bb2 = bvs[rh * 4][lo]; int ii = bis[rh * 4][lo];
        #pragma unroll
        for (int q = 1; q < 4; ++q) {
            float ov = bvs[rh * 4 + q][lo]; int oi = bis[rh * 4 + q][lo];
            if (ov < bb2 || (ov == bb2 && oi < ii)) { bb2 = ov; ii = oi; }
        }
        idxl[tid] = ii;
        out_idxf[rbase + tid] = (float)ii;
        atomicAdd(&counts[ii], 1.0f);
    }
    __syncthreads();

    // ---- fused quant phase (r16-verified patterns, 64 rows) ----
    #pragma unroll
    for (int v = 0; v < 2; ++v) {
        int n  = wid * 8 + v * 4 + (l >> 4);     // 4 rows per instr
        int d4 = (l & 15) << 2;
        *(float4*)&q32[n][d4] = *(const float4*)(w + idxl[n] * 64 + d4);
    }
    __syncthreads();

    float ll = 0.f;
    #pragma unroll
    for (int p = 0; p < 8; ++p) {
        int e = p * 512 + tid;
        int nn = e & 63, d = e >> 6;
        float q  = q32[nn][d];
        float xv = x32[nn][d];
        float dd = q - xv;
        ll += dd * dd;
        outq[b * 65536 + d * 1024 + hw0 + nn] = q;   // coalesced
    }
    #pragma unroll
    for (int off = 32; off; off >>= 1) ll += __shfl_down(ll, off);
    if (l == 0) red[wid] = ll;
    __syncthreads();
    if (tid == 0) {
        float s = 0.f;
        #pragma unroll
        for (int i = 0; i < 8; ++i) s += red[i];
        atomicAdd(loss, s);
    }

    // dw: lane = d, one coalesced 256B atomic row per vector (8 rows/wave)
    #pragma unroll
    for (int v = 0; v < 8; ++v) {
        int n = wid * 8 + v;
        atomicAdd(&dw[idxl[n] * 64 + l], x32[n][l]);
    }
}

// =====================================================================
// kernel 2 (merged finalize, round-9-verified)
// =====================================================================
__global__ __launch_bounds__(256)
void k_final(const float* __restrict__ ema_cs, const float* __restrict__ ema_w,
             const float* __restrict__ counts, const float* __restrict__ dw,
             const float* __restrict__ loss, float* __restrict__ out) {
    __shared__ float cs[1024];
    __shared__ float redA[4], redB[4];
    int tid = threadIdx.x;

    float necs[4];
    float s1 = 0.f, s2 = 0.f;
    #pragma unroll
    for (int q = 0; q < 4; ++q) {
        int j = q * 256 + tid;
        float c  = counts[j];
        float ne = 0.99f * ema_cs[j] + 0.01f * c;
        necs[q] = ne;
        float p = c * (1.0f / 32768.0f);
        s1 += ne;
        s2 += -p * logf(p + 1e-10f);
    }
    #pragma unroll
    for (int off = 32; off; off >>= 1) {
        s1 += __shfl_down(s1, off);
        s2 += __shfl_down(s2, off);
    }
    if ((tid & 63) == 0) { redA[tid >> 6] = s1; redB[tid >> 6] = s2; }
    __syncthreads();
    float ntot = redA[0] + redA[1] + redA[2] + redA[3];
    #pragma unroll
    for (int q = 0; q < 4; ++q)
        cs[q * 256 + tid] = (necs[q] + 1e-5f) / (ntot + 1024.0f * 1e-5f) * ntot;

    if (blockIdx.x == 0) {
        #pragma unroll
        for (int q = 0; q < 4; ++q) out[O_NECS + q * 256 + tid] = necs[q];
        if (tid == 0) {
            out[O_PERP] = expf(redB[0] + redB[1] + redB[2] + redB[3]);
            out[O_LOSS] = 0.25f * loss[0] * (1.0f / 2097152.0f);
        }
    }
    __syncthreads();

    int f = blockIdx.x * 256 + tid;
    int j = f >> 6;
    float ne = 0.99f * ema_w[f] + 0.01f * dw[f];
    out[O_EMAW + f] = ne;
    out[O_W + f]    = ne / cs[j];
}

// =====================================================================
extern "C" void kernel_launch(void* const* d_in, const int* in_sizes, int n_in,
                              void* d_out, int out_size, void* d_ws, size_t ws_size,
                              hipStream_t stream) {
    const float* x      = (const float*)d_in[0];
    const float* w      = (const float*)d_in[1];
    const float* ema_cs = (const float*)d_in[2];
    const float* ema_w  = (const float*)d_in[3];
    float* out = (float*)d_out;
    float* ws  = (float*)d_ws;

    _Float16* wbf  = (_Float16*)(ws + W_WBF);
    float* wsq     = ws + W_SW2;
    float* rsqb    = ws + W_RSQ;
    float* counts  = ws + W_CNT;
    float* dwb     = ws + W_DW;
    float* lossb   = ws + W_LOSS;

    k_prep <<<256, 256, 0, stream>>>(w, x, wbf, wsq, rsqb, counts);
    k_dist <<<512, 512, 0, stream>>>(x, wbf, wsq, rsqb, w,
                                     out + O_IDX, out + O_Q, counts, dwb, lossb);
    k_final<<<256, 256, 0, stream>>>(ema_cs, ema_w, counts, dwb, lossb, out);
}

// Round 18
// 47.072 us; speedup vs baseline: 1.4249x; 1.1325x over previous
//
#include <hip/hip_runtime.h>
#include <math.h>

typedef _Float16 half8 __attribute__((ext_vector_type(8)));
typedef _Float16 half4v __attribute__((ext_vector_type(4)));
typedef float    f32x4 __attribute__((ext_vector_type(4)));

// ---------------- output offsets (floats) ----------------
#define O_Q     0
#define O_LOSS  2097152
#define O_IDX   2097153
#define O_PERP  2129921
#define O_NECS  2129922
#define O_EMAW  2130946
#define O_W     2196482

// ---------------- workspace offsets (4-byte units) ----------------
#define W_WBF    0          // 65536 fl (=131072 halfs): B-fragments [64ct][4j][64l][8e]
#define W_SW2    65536      // 1024  wsq  (fl32 of fp64 sum)
#define W_RSQ    66560      // 32768 rsq  (fl32 of fp64 sum)
#define W_CNT    132096     // 1024  counts
#define W_DW     133120     // 65536 dw
#define W_LOSS   198656     // 1     loss
#define W_ZN     66561      // floats to zero starting at W_CNT

#define F16_MIN_NORM 6.103515625e-05f   // 2^-14

// =====================================================================
// kernel 0 (prep, grid 256): unchanged from round 10 (verified)
// =====================================================================
__global__ __launch_bounds__(256)
void k_prep(const float* __restrict__ w, const float* __restrict__ x,
            _Float16* __restrict__ wbf, float* __restrict__ wsq,
            float* __restrict__ rsq, float* __restrict__ zbase) {
    __shared__ float sh[64][65];
    int tid = threadIdx.x, blk = blockIdx.x;

    for (int z = blk * 256 + tid; z < W_ZN; z += 256 * 256) zbase[z] = 0.f;

    if (blk < 64) {
        int T  = blk * 256 + tid;           // 0..16383
        int ct = T >> 8, j = (T >> 6) & 3, l = T & 63;
        int kb = j & 1, isLo = j >> 1;
        int c  = ct * 16 + (l & 15), g = l >> 4;
        half8 o;
        #pragma unroll
        for (int e = 0; e < 8; ++e) {
            int kd = kb * 32 + g * 4 + (e & 3) + ((e >> 2) << 4);
            float wv = w[c * 64 + kd];
            _Float16 h = (fabsf(wv) >= F16_MIN_NORM) ? (_Float16)wv : (_Float16)0.f;
            if (isLo) {
                float hf = (float)h;
                o[e] = (_Float16)((wv - hf) * 16384.0f);   // lo scaled 2^14
            } else {
                o[e] = h;
            }
        }
        *(half8*)(wbf + ((ct * 4 + j) * 64 + l) * 8) = o;
    }

    if (blk < 16) {           // wsq
        int j0 = blk * 64;
        for (int p = 0; p < 16; ++p) {
            int f = p * 256 + tid;
            int j = f >> 6, d = f & 63;
            sh[j][d] = w[(j0 + j) * 64 + d];
        }
        __syncthreads();
        if (tid < 64) {
            double s = 0.0;
            #pragma unroll
            for (int d = 0; d < 64; ++d) {
                double v = (double)sh[tid][d];
                s = fma(v, v, s);
            }
            wsq[j0 + tid] = (float)s;
        }
    }

    if (blk >= 128) {         // rsq, one row per thread, d ascending
        int r = (blk - 128) * 256 + tid;
        const float* xp = x + (r >> 10) * 65536 + (r & 1023);
        double s = 0.0;
        #pragma unroll 8
        for (int d = 0; d < 64; ++d) {
            double v = (double)xp[d * 1024];
            s = fma(v, v, s);
        }
        rsq[r] = (float)s;
    }
}

// =====================================================================
// kernel 1 (fused): MFMA distances + argmin + quant/loss/counts/dw.
// 64-rows/block register-B: grid 512 x 256 thr (4 waves). Wave = one
// ct-QUARTER (16 cts) x ALL 4 row-tiles -> each B-load set feeds 24
// MFMAs (~600cy compute per load set hides L2 latency; wbf traffic
// 128 MB). launch_bounds(256,3): VGPR cap ~170 > ~155 live state (the
// r16 failure was cap 85 < liveness). LDS ~51 KB -> 3 blocks/CU.
// Per-(row,ct) score numerics bitwise-identical to rounds 10-17; merge
// over wid-ascending disjoint ct-quarters, strict < => global first-min.
// =====================================================================
__global__ __launch_bounds__(256, 3)
void k_dist(const float* __restrict__ x, const _Float16* __restrict__ wbf,
            const float* __restrict__ wsq, const float* __restrict__ rsq_g,
            const float* __restrict__ w,
            float* __restrict__ out_idxf,
            float* __restrict__ outq, float* __restrict__ counts,
            float* __restrict__ dw, float* __restrict__ loss) {
    __shared__ _Float16 xhi[64 * 64];     // 8 KB  [kd][row]
    __shared__ _Float16 xlo[64 * 64];     // 8 KB
    __shared__ float x32[64][65];         // 16.6 KB
    __shared__ float q32[64][65];         // 16.6 KB
    __shared__ float bvs[4][64];
    __shared__ int   bis[4][64];
    __shared__ int   idxl[64];
    __shared__ float red[4];
    int tid = threadIdx.x;
    int rbase = blockIdx.x * 64;
    int b = rbase >> 10, hw0 = rbase & 1023;
    const float* xb = x + b * 65536 + hw0;

    // stage 64 rows -> f16 hi/lo (xlo scaled 2^11) + fp32 copy
    #pragma unroll
    for (int p = 0; p < 4; ++p) {
        int f = p * 256 + tid;
        int d = f >> 4, r4 = (f & 15) << 2;
        float4 v = *(const float4*)(xb + d * 1024 + r4);
        float vv[4] = {v.x, v.y, v.z, v.w};
        half4v h, lo;
        #pragma unroll
        for (int q = 0; q < 4; ++q) {
            float xv = vv[q];
            _Float16 hh = (fabsf(xv) >= F16_MIN_NORM) ? (_Float16)xv : (_Float16)0.f;
            h[q]  = hh;
            lo[q] = (_Float16)((xv - (float)hh) * 2048.0f);
            x32[r4 + q][d] = xv;
        }
        *(half4v*)&xhi[d * 64 + r4] = h;
        *(half4v*)&xlo[d * 64 + r4] = lo;
    }
    __syncthreads();

    int l   = tid & 63;
    int wid = tid >> 6;          // ct-quarter of this wave (0..3)
    int g = l >> 4, n16 = l & 15;

    // A fragments for ALL 4 row-tiles (resident for the whole ct loop)
    half8 ahi[4][2], alo[4][2];
    #pragma unroll
    for (int t = 0; t < 4; ++t)
        #pragma unroll
        for (int kb = 0; kb < 2; ++kb) {
            #pragma unroll
            for (int e = 0; e < 8; ++e) {
                int kd = kb * 32 + g * 4 + (e & 3) + ((e >> 2) << 4);
                ahi[t][kb][e] = xhi[kd * 64 + t * 16 + n16];
                alo[t][kb][e] = xlo[kd * 64 + t * 16 + n16];
            }
        }

    float rq[4][4];
    #pragma unroll
    for (int t = 0; t < 4; ++t)
        #pragma unroll
        for (int i = 0; i < 4; ++i)
            rq[t][i] = rsq_g[rbase + t * 16 + g * 4 + i];

    float best[4][4];
    int   bidx[4][4];
    #pragma unroll
    for (int t = 0; t < 4; ++t)
        #pragma unroll
        for (int i = 0; i < 4; ++i) { best[t][i] = 3.4e38f; bidx[t][i] = 0; }

    const half8* wv8 = (const half8*)wbf;
    #pragma unroll 1
    for (int c8 = 0; c8 < 16; ++c8) {
        int ct = wid * 16 + c8;
        const half8* wb = wv8 + ct * 256 + l;
        half8 bh0 = wb[0], bh1 = wb[64], bl0 = wb[128], bl1 = wb[192];
        float wsqv = wsq[ct * 16 + n16];
        int n = ct * 16 + n16;

        #pragma unroll
        for (int t = 0; t < 4; ++t) {
            f32x4 c1 = {0.f, 0.f, 0.f, 0.f};
            f32x4 c2 = {0.f, 0.f, 0.f, 0.f};
            f32x4 c3 = {0.f, 0.f, 0.f, 0.f};
            c1 = __builtin_amdgcn_mfma_f32_16x16x32_f16(ahi[t][0], bh0, c1, 0, 0, 0);
            c1 = __builtin_amdgcn_mfma_f32_16x16x32_f16(ahi[t][1], bh1, c1, 0, 0, 0);
            c2 = __builtin_amdgcn_mfma_f32_16x16x32_f16(alo[t][0], bh0, c2, 0, 0, 0);
            c2 = __builtin_amdgcn_mfma_f32_16x16x32_f16(alo[t][1], bh1, c2, 0, 0, 0);
            c3 = __builtin_amdgcn_mfma_f32_16x16x32_f16(ahi[t][0], bl0, c3, 0, 0, 0);
            c3 = __builtin_amdgcn_mfma_f32_16x16x32_f16(ahi[t][1], bl1, c3, 0, 0, 0);

            #pragma unroll
            for (int i = 0; i < 4; ++i) {
                float dot = fmaf(c2[i], 4.8828125e-4f, c1[i]);      // +C2*2^-11
                dot = fmaf(c3[i], 6.103515625e-05f, dot);           // +C3*2^-14
                float t1 = rq[t][i] + wsqv;                         // fl32 add @ ~64
                float sc = fmaf(dot, -2.0f, t1);                    // one rounding
                if (sc < best[t][i]) { best[t][i] = sc; bidx[t][i] = n; }
            }
        }
    }

    // reduce across the 16 lanes of each group (tie -> lower index)
    #pragma unroll
    for (int off = 1; off < 16; off <<= 1) {
        #pragma unroll
        for (int t = 0; t < 4; ++t)
            #pragma unroll
            for (int i = 0; i < 4; ++i) {
                float ov = __shfl_xor(best[t][i], off);
                int   oi = __shfl_xor(bidx[t][i], off);
                if (ov < best[t][i] || (ov == best[t][i] && oi < bidx[t][i])) {
                    best[t][i] = ov; bidx[t][i] = oi;
                }
            }
    }
    if (n16 == 0) {
        #pragma unroll
        for (int t = 0; t < 4; ++t)
            #pragma unroll
            for (int i = 0; i < 4; ++i) {
                bvs[wid][t * 16 + g * 4 + i] = best[t][i];
                bis[wid][t * 16 + g * 4 + i] = bidx[t][i];
            }
    }
    __syncthreads();

    // merge ct-quarters per row (wid ascending = ct ascending -> first-min)
    if (tid < 64) {
        float bb = bvs[0][tid]; int ii = bis[0][tid];
        #pragma unroll
        for (int q = 1; q < 4; ++q) {
            float ov = bvs[q][tid]; int oi = bis[q][tid];
            if (ov < bb) { bb = ov; ii = oi; }
        }
        idxl[tid] = ii;
        out_idxf[rbase + tid] = (float)ii;
        atomicAdd(&counts[ii], 1.0f);
    }
    __syncthreads();

    // ---- fused quant phase (r17-verified 64-row patterns, 4 waves) ----
    #pragma unroll
    for (int v = 0; v < 4; ++v) {
        int n  = wid * 16 + v * 4 + (l >> 4);    // 4 rows per instr
        int d4 = (l & 15) << 2;
        *(float4*)&q32[n][d4] = *(const float4*)(w + idxl[n] * 64 + d4);
    }
    __syncthreads();

    float ll = 0.f;
    #pragma unroll
    for (int p = 0; p < 16; ++p) {
        int e = p * 256 + tid;
        int nn = e & 63, d = e >> 6;
        float q  = q32[nn][d];
        float xv = x32[nn][d];
        float dd = q - xv;
        ll += dd * dd;
        outq[b * 65536 + d * 1024 + hw0 + nn] = q;   // coalesced
    }
    #pragma unroll
    for (int off = 32; off; off >>= 1) ll += __shfl_down(ll, off);
    if (l == 0) red[wid] = ll;
    __syncthreads();
    if (tid == 0) atomicAdd(loss, red[0] + red[1] + red[2] + red[3]);

    // dw: lane = d, one coalesced 256B atomic row per vector (16 rows/wave)
    #pragma unroll
    for (int v = 0; v < 16; ++v) {
        int n = wid * 16 + v;
        atomicAdd(&dw[idxl[n] * 64 + l], x32[n][l]);
    }
}

// =====================================================================
// kernel 2 (merged finalize, round-9-verified)
// =====================================================================
__global__ __launch_bounds__(256)
void k_final(const float* __restrict__ ema_cs, const float* __restrict__ ema_w,
             const float* __restrict__ counts, const float* __restrict__ dw,
             const float* __restrict__ loss, float* __restrict__ out) {
    __shared__ float cs[1024];
    __shared__ float redA[4], redB[4];
    int tid = threadIdx.x;

    float necs[4];
    float s1 = 0.f, s2 = 0.f;
    #pragma unroll
    for (int q = 0; q < 4; ++q) {
        int j = q * 256 + tid;
        float c  = counts[j];
        float ne = 0.99f * ema_cs[j] + 0.01f * c;
        necs[q] = ne;
        float p = c * (1.0f / 32768.0f);
        s1 += ne;
        s2 += -p * logf(p + 1e-10f);
    }
    #pragma unroll
    for (int off = 32; off; off >>= 1) {
        s1 += __shfl_down(s1, off);
        s2 += __shfl_down(s2, off);
    }
    if ((tid & 63) == 0) { redA[tid >> 6] = s1; redB[tid >> 6] = s2; }
    __syncthreads();
    float ntot = redA[0] + redA[1] + redA[2] + redA[3];
    #pragma unroll
    for (int q = 0; q < 4; ++q)
        cs[q * 256 + tid] = (necs[q] + 1e-5f) / (ntot + 1024.0f * 1e-5f) * ntot;

    if (blockIdx.x == 0) {
        #pragma unroll
        for (int q = 0; q < 4; ++q) out[O_NECS + q * 256 + tid] = necs[q];
        if (tid == 0) {
            out[O_PERP] = expf(redB[0] + redB[1] + redB[2] + redB[3]);
            out[O_LOSS] = 0.25f * loss[0] * (1.0f / 2097152.0f);
        }
    }
    __syncthreads();

    int f = blockIdx.x * 256 + tid;
    int j = f >> 6;
    float ne = 0.99f * ema_w[f] + 0.01f * dw[f];
    out[O_EMAW + f] = ne;
    out[O_W + f]    = ne / cs[j];
}

// =====================================================================
extern "C" void kernel_launch(void* const* d_in, const int* in_sizes, int n_in,
                              void* d_out, int out_size, void* d_ws, size_t ws_size,
                              hipStream_t stream) {
    const float* x      = (const float*)d_in[0];
    const float* w      = (const float*)d_in[1];
    const float* ema_cs = (const float*)d_in[2];
    const float* ema_w  = (const float*)d_in[3];
    float* out = (float*)d_out;
    float* ws  = (float*)d_ws;

    _Float16* wbf  = (_Float16*)(ws + W_WBF);
    float* wsq     = ws + W_SW2;
    float* rsqb    = ws + W_RSQ;
    float* counts  = ws + W_CNT;
    float* dwb     = ws + W_DW;
    float* lossb   = ws + W_LOSS;

    k_prep <<<256, 256, 0, stream>>>(w, x, wbf, wsq, rsqb, counts);
    k_dist <<<512, 256, 0, stream>>>(x, wbf, wsq, rsqb, w,
                                     out + O_IDX, out + O_Q, counts, dwb, lossb);
    k_final<<<256, 256, 0, stream>>>(ema_cs, ema_w, counts, dwb, lossb, out);
}